// Round 3
// baseline (148.311 us; speedup 1.0000x reference)
//
#include <hip/hip_runtime.h>

#define N_NODES 50000
#define N_EDGES 800000
#define F 64
#define CHUNK 3072       // edges per partition workgroup (R17: 262 blocks > 256 CUs)
#define NWG1 ((N_EDGES + CHUNK - 1) / CHUNK)   // 261
#define NBUCK 196        // coarse buckets: dst >> 8
#define BSTRIDE 8192     // fixed per-bucket capacity (mean 4082, sigma ~64)
#define NWTILE (N_NODES / 16)   // 3125 exact

typedef __attribute__((ext_vector_type(8))) _Float16 half8;   // 16 B
typedef __attribute__((ext_vector_type(4))) float f32x4;
typedef __attribute__((ext_vector_type(8))) unsigned short ushort8v; // 16 B

// ---------- K1: partition into fixed-capacity buckets + f16 convert + W prep ----
__global__ __launch_bounds__(256) void partition_conv(
    const int*    __restrict__ src, const int* __restrict__ dst,
    const float4* __restrict__ xin,      // [N*16] float4 view of x
    half8*        __restrict__ x16,      // [N*8] f16 rows
    const float*  __restrict__ W1, const float* __restrict__ W2,
    _Float16*     __restrict__ Wt1, _Float16* __restrict__ Wt2,
    unsigned*     __restrict__ bcur,     // [256] zeroed cursors
    unsigned*     __restrict__ ebuf) {   // [NBUCK*BSTRIDE] strided buckets
  int t = threadIdx.x, b = blockIdx.x;
  if (b == NWG1) {                       // W prep block
    for (int i = t; i < 64 * 128; i += 256) {
      int n = i >> 7, k = i & 127;       // Wt[n][k] = W[k][n]
      Wt1[i] = (_Float16)W1[k * 64 + n];
      Wt2[i] = (_Float16)W2[k * 64 + n];
    }
    return;
  }
  __shared__ int hist[256], lscan[256], lcur[256], gbase[256];
  __shared__ unsigned stage[CHUNK];      // 12 KB
  hist[t] = 0; __syncthreads();
  int e0 = b * CHUNK;
  int cnt = N_EDGES - e0; if (cnt > CHUNK) cnt = CHUNK;
  for (int i = t; i < cnt; i += 256) atomicAdd(&hist[dst[e0 + i] >> 8], 1);

  // f32 -> f16 feature conversion, grid-stride
  const int TOT = N_NODES * F / 8;
  for (int i = b * 256 + t; i < TOT; i += NWG1 * 256) {
    float4 a = xin[i * 2], c = xin[i * 2 + 1];
    half8 hh;
    hh[0] = (_Float16)a.x; hh[1] = (_Float16)a.y;
    hh[2] = (_Float16)a.z; hh[3] = (_Float16)a.w;
    hh[4] = (_Float16)c.x; hh[5] = (_Float16)c.y;
    hh[6] = (_Float16)c.z; hh[7] = (_Float16)c.w;
    x16[i] = hh;
  }
  __syncthreads();

  int v = hist[t];
  lscan[t] = v; __syncthreads();
  for (int off = 1; off < 256; off <<= 1) {
    int a = (t >= off) ? lscan[t - off] : 0;
    __syncthreads();
    lscan[t] += a;
    __syncthreads();
  }
  lscan[t] -= v;                         // exclusive local scan
  lcur[t] = lscan[t];
  if (v > 0) gbase[t] = (int)atomicAdd(&bcur[t], (unsigned)v);  // in-bucket base
  __syncthreads();

  for (int i = t; i < cnt; i += 256) {
    int d = dst[e0 + i], s = src[e0 + i];
    int bb = d >> 8;
    int p = atomicAdd(&lcur[bb], 1);
    stage[p] = ((unsigned)bb << 24) | ((unsigned)(d & 255) << 16) | (unsigned)s;
  }
  __syncthreads();
  for (int i = t; i < cnt; i += 256) {
    unsigned e = stage[i];
    int bb = e >> 24;
    ebuf[bb * BSTRIDE + gbase[bb] + (i - lscan[bb])] = e;   // coalesced runs
  }
}

// ---------- K2: per-bucket counting sort, split by key half-range ----------
// (R19) Per-node segments PADDED to multiples of 8 (pad id = 0, masked out by
// deg at consume time) so every row_start is 16B-aligned -> layer kernel can
// vector-load edge ids (ushort8). Halves write to fixed offsets 0 / BSTRIDE/2.
// Capacity: half ~2041+-45 edges + <=896 pad < 4096. srt = 8 KB.
__global__ __launch_bounds__(256) void bucket_sort(
    const unsigned* __restrict__ ebuf, const unsigned* __restrict__ bcur,
    unsigned short* __restrict__ edge_src, int* __restrict__ row_start,
    int* __restrict__ deg) {
  __shared__ int lhist[128], lscan[128], lcur[128];
  __shared__ unsigned short srt[BSTRIDE / 2];    // 8 KB
  int B = blockIdx.x, t = threadIdx.x;
  int b = B >> 1, h = B & 1;
  int s0 = b * BSTRIDE;
  int cnt = (int)bcur[b];

  if (t < 128) lhist[t] = 0;
  __syncthreads();
  for (int i = t; i < cnt; i += 256) {
    int bin = (int)((ebuf[s0 + i] >> 16) & 255);
    if ((bin >> 7) == h) atomicAdd(&lhist[bin & 127], 1);
  }
  __syncthreads();

  int v  = (t < 128) ? lhist[t] : 0;
  int pv = (v + 7) & ~7;                 // padded segment size (8-aligned)
  if (t < 128) lscan[t] = pv;
  __syncthreads();
  for (int off = 1; off < 128; off <<= 1) {
    int a = (t >= off && t < 128) ? lscan[t - off] : 0;
    __syncthreads();
    if (t < 128) lscan[t] += a;
    __syncthreads();
  }
  if (t < 128) { lscan[t] -= pv; lcur[t] = lscan[t]; }   // exclusive padded scan
  __syncthreads();

  int total_p = lscan[127] + ((lhist[127] + 7) & ~7);    // padded half size
  int base    = h * (BSTRIDE / 2);                       // fixed half offset

  for (int i = t; i < cnt; i += 256) {
    unsigned e = ebuf[s0 + i];
    int bin = (int)((e >> 16) & 255);
    if ((bin >> 7) == h) {
      int p = atomicAdd(&lcur[bin & 127], 1);
      srt[p] = (unsigned short)(e & 0xFFFFu);
    }
  }
  __syncthreads();
  if (t < 128) {                          // zero-fill pad slots (valid node id 0)
    int p0 = lscan[t];
    for (int j = v; j < pv; ++j) srt[p0 + j] = 0;
  }
  __syncthreads();

  for (int i = t; i < total_p; i += 256) edge_src[s0 + base + i] = srt[i];  // 2B coalesced

  if (t < 128) {
    int n = b * 256 + h * 128 + t;
    if (n < N_NODES) { row_start[n] = s0 + base + lscan[t]; deg[n] = v; }
  }
}

// ---------- fused layer: octet-per-node aggregate -> LDS -> MFMA linear ----------
// Block = 4 waves = 32 nodes = 2 MFMA tiles.
// Phase 1 (R19): 16-deep software pipeline. Edge ids come from ONE 16B ushort8
//   vector load per 8 edges (row_start 16B-aligned via K2 padding); 16 feature
//   gathers (16B each) in flight per lane; next batch's id vectors prefetched
//   under the gather latency. All temporaries are named scalars (no runtime-
//   indexed arrays -> no scratch). Accumulation order over real edges is
//   unchanged (pads masked by exact deg) => bitwise-identical result.
// Phase 2: MFMA linear; wave w does nt-half (w&1) of tile (w>>1).
__global__ __launch_bounds__(256) void sage_layer_fused(
    const half8*    __restrict__ feat16,    // [N,8] gather source (= self16)
    const _Float16* __restrict__ self16,    // [N,64]
    const int*      __restrict__ row_start,
    const int*      __restrict__ deg,
    const unsigned short* __restrict__ edge_src,
    const _Float16* __restrict__ Wt,        // [64,128]  Wt[n][k] = W[k][n]
    const float*    __restrict__ bias,      // [64]
    float*          __restrict__ outf,      // [N,64] f32 or null
    unsigned short* __restrict__ out16,     // [N,64] f16 or null
    int do_relu) {
  __shared__ _Float16 lmean[32 * 72];       // node stride 72 halves, 4.6 KB
  int t = threadIdx.x;
  int w = t >> 6, lane = t & 63;

  // ---- phase 1: aggregate 8 nodes per wave (octet-per-node, 16-deep) ----
  {
    int o = lane >> 3, q = lane & 7;
    int n = blockIdx.x * 32 + w * 8 + o;
    if (n < N_NODES) {
      int start = row_start[n];            // multiple of 8 (16B-aligned)
      int d     = deg[n];
      half8 acc8 = (half8){0, 0, 0, 0, 0, 0, 0, 0};
      if (d > 0) {
        const ushort8v* idp = (const ushort8v*)(edge_src + start);
        int nb = (d + 15) >> 4;            // 16-edge batches
        // idp[2b+1] may read past this node's padded segment; stays inside
        // edge_src allocation (bounded above by bucket stride), values are
        // valid node ids or 0-pad, and are masked out of the accumulate.
        ushort8v iA = idp[0], iB = idp[1];
        for (int b = 0; b < nb; ++b) {
          half8 h0 = feat16[(size_t)iA[0] * 8 + q];
          half8 h1 = feat16[(size_t)iA[1] * 8 + q];
          half8 h2 = feat16[(size_t)iA[2] * 8 + q];
          half8 h3 = feat16[(size_t)iA[3] * 8 + q];
          half8 h4 = feat16[(size_t)iA[4] * 8 + q];
          half8 h5 = feat16[(size_t)iA[5] * 8 + q];
          half8 h6 = feat16[(size_t)iA[6] * 8 + q];
          half8 h7 = feat16[(size_t)iA[7] * 8 + q];
          half8 h8 = feat16[(size_t)iB[0] * 8 + q];
          half8 h9 = feat16[(size_t)iB[1] * 8 + q];
          half8 hA = feat16[(size_t)iB[2] * 8 + q];
          half8 hB = feat16[(size_t)iB[3] * 8 + q];
          half8 hC = feat16[(size_t)iB[4] * 8 + q];
          half8 hD = feat16[(size_t)iB[5] * 8 + q];
          half8 hE = feat16[(size_t)iB[6] * 8 + q];
          half8 hF = feat16[(size_t)iB[7] * 8 + q];
          ushort8v nA, nB;
          if (b + 1 < nb) {                // prefetch next batch's id vectors
            nA = idp[2 * b + 2];
            nB = idp[2 * b + 3];
          }
          int b0 = b * 16;
          if (b0 + 16 <= d) {              // full batch: unconditional adds
            acc8 += h0; acc8 += h1; acc8 += h2; acc8 += h3;
            acc8 += h4; acc8 += h5; acc8 += h6; acc8 += h7;
            acc8 += h8; acc8 += h9; acc8 += hA; acc8 += hB;
            acc8 += hC; acc8 += hD; acc8 += hE; acc8 += hF;
          } else {                          // tail: masked adds (order kept)
            if (b0 +  0 < d) acc8 += h0;
            if (b0 +  1 < d) acc8 += h1;
            if (b0 +  2 < d) acc8 += h2;
            if (b0 +  3 < d) acc8 += h3;
            if (b0 +  4 < d) acc8 += h4;
            if (b0 +  5 < d) acc8 += h5;
            if (b0 +  6 < d) acc8 += h6;
            if (b0 +  7 < d) acc8 += h7;
            if (b0 +  8 < d) acc8 += h8;
            if (b0 +  9 < d) acc8 += h9;
            if (b0 + 10 < d) acc8 += hA;
            if (b0 + 11 < d) acc8 += hB;
            if (b0 + 12 < d) acc8 += hC;
            if (b0 + 13 < d) acc8 += hD;
            if (b0 + 14 < d) acc8 += hE;
            if (b0 + 15 < d) acc8 += hF;
          }
          if (b + 1 < nb) { iA = nA; iB = nB; }
        }
      }
      float inv = (d > 0) ? 1.0f / (float)d : 0.0f;
      half8 hm;
      #pragma unroll
      for (int k = 0; k < 8; ++k) hm[k] = (_Float16)((float)acc8[k] * inv);
      *(half8*)&lmean[(w * 8 + o) * 72 + q * 8] = hm;
    }
  }
  __syncthreads();

  // ---- phase 2: MFMA linear; wave w does nt-half (w&1) of tile (w>>1) ----
  int tile = w >> 1;
  int wt = blockIdx.x * 2 + tile;
  if (wt >= NWTILE) return;
  int m = lane & 15, quad = lane >> 4;
  size_t arow = (size_t)(wt * 16 + m) * 64 + quad * 8;
  half8 a0 = *(const half8*)(self16 + arow);
  half8 a1 = *(const half8*)(self16 + arow + 32);
  int ln = tile * 16 + m;                   // local node 0..31
  half8 a2 = *(const half8*)&lmean[ln * 72 + quad * 8];
  half8 a3 = *(const half8*)&lmean[ln * 72 + quad * 8 + 32];

  int nt0 = (w & 1) * 2;                    // 0 or 2
  #pragma unroll
  for (int i = 0; i < 2; ++i) {
    int nt = nt0 + i;
    float bv = bias[nt * 16 + m];           // col = lane&15
    f32x4 acc = (f32x4){bv, bv, bv, bv};
    const _Float16* wrow = Wt + (size_t)(nt * 16 + m) * 128 + quad * 8;
    half8 b0 = *(const half8*)(wrow);
    half8 b1 = *(const half8*)(wrow + 32);
    half8 b2 = *(const half8*)(wrow + 64);
    half8 b3 = *(const half8*)(wrow + 96);
    acc = __builtin_amdgcn_mfma_f32_16x16x32_f16(a0, b0, acc, 0, 0, 0);
    acc = __builtin_amdgcn_mfma_f32_16x16x32_f16(a1, b1, acc, 0, 0, 0);
    acc = __builtin_amdgcn_mfma_f32_16x16x32_f16(a2, b2, acc, 0, 0, 0);
    acc = __builtin_amdgcn_mfma_f32_16x16x32_f16(a3, b3, acc, 0, 0, 0);
    #pragma unroll
    for (int r = 0; r < 4; ++r) {
      size_t off = (size_t)(wt * 16 + quad * 4 + r) * 64 + nt * 16 + m;
      float v = acc[r];
      if (do_relu) v = fmaxf(v, 0.0f);
      if (outf)  outf[off] = v;
      if (out16) { _Float16 hv = (_Float16)v; out16[off] = *(unsigned short*)&hv; }
    }
  }
}

extern "C" void kernel_launch(void* const* d_in, const int* in_sizes, int n_in,
                              void* d_out, int out_size, void* d_ws, size_t ws_size,
                              hipStream_t stream) {
  const float* x  = (const float*)d_in[0];
  const int*   ei = (const int*)d_in[1];   // [2,E]: row 0 = src, row 1 = dst
  const float* W1 = (const float*)d_in[2];
  const float* b1 = (const float*)d_in[3];
  const float* W2 = (const float*)d_in[4];
  const float* b2 = (const float*)d_in[5];
  float* out = (float*)d_out;

  const int* src = ei;
  const int* dst = ei + N_EDGES;

  // ws layout (int offsets), all 16B-aligned (R14 proven):
  //   bcur@0[256] | deg@256[50048] | row_start@50304[50048] |
  //   edge_src@100352[196*8192 ushorts = 802816 ints] | ebuf@903168[1605632] |
  //   x16@2508800[1600000] | h116@4108800[1600000] |
  //   Wt1@5708800[4096] | Wt2@5712896[4096]   total 5,716,992 ints = 22.9 MB
  int* wsi       = (int*)d_ws;
  unsigned* bcur = (unsigned*)wsi;
  int* deg       = wsi + 256;
  int* row_start = wsi + 50304;
  unsigned short* edge_src = (unsigned short*)(wsi + 100352);
  unsigned* ebuf = (unsigned*)(wsi + 903168);
  half8* x16     = (half8*)(wsi + 2508800);
  unsigned short* h116 = (unsigned short*)(wsi + 4108800);
  _Float16* Wt1  = (_Float16*)(wsi + 5708800);
  _Float16* Wt2  = (_Float16*)(wsi + 5712896);

  hipMemsetAsync(bcur, 0, 256 * sizeof(unsigned), stream);

  dim3 blk(256);
  partition_conv<<<NWG1 + 1, blk, 0, stream>>>(
      src, dst, (const float4*)x, x16, W1, W2, Wt1, Wt2, bcur, ebuf);
  bucket_sort<<<NBUCK * 2, blk, 0, stream>>>(ebuf, bcur, edge_src, row_start, deg);

  dim3 grd_fused((N_NODES + 31) / 32);   // 1563 blocks = 3126 tiles >= 3125

  // Layer 1: h1 = relu([x||mean]W1+b1), kept only as f16
  sage_layer_fused<<<grd_fused, blk, 0, stream>>>(
      x16, (const _Float16*)x16, row_start, deg, edge_src,
      Wt1, b1, nullptr, h116, 1);
  // Layer 2: out = [h1||mean]W2+b2 (f32)
  sage_layer_fused<<<grd_fused, blk, 0, stream>>>(
      (const half8*)h116, (const _Float16*)h116, row_start, deg, edge_src,
      Wt2, b2, out, nullptr, 0);
}